// Round 11
// baseline (375.824 us; speedup 1.0000x reference)
//
#include <hip/hip_runtime.h>
#include <hip/hip_bf16.h>

#define NM 50000
#define HD 128
#define KNEI 8
#define BM 64
#define NBLK ((NM + BM - 1) / BM)   // 782
#define NH ((size_t)NM * (size_t)HD)

typedef float  fx4   __attribute__((ext_vector_type(4)));
typedef short  s16x8 __attribute__((ext_vector_type(8)));
typedef short  s16x4 __attribute__((ext_vector_type(4)));

__device__ __forceinline__ float sigm_f(float x) {
    return __builtin_amdgcn_rcpf(1.0f + __expf(-x));
}
__device__ __forceinline__ float tanh_f(float x) {
    return 2.0f * sigm_f(2.0f * x) - 1.0f;
}
__device__ __forceinline__ unsigned short f2b(float f) {
    __hip_bfloat16 h = __float2bfloat16(f);
    return __builtin_bit_cast(unsigned short, h);
}
__device__ __forceinline__ float b2f(unsigned short u) {
    __hip_bfloat16 h = __builtin_bit_cast(__hip_bfloat16, u);
    return __bfloat162float(h);
}

#define MFMA16(a, b, c) __builtin_amdgcn_mfma_f32_16x16x32_bf16(a, b, c, 0, 0, 0)

// ---- swizzled LDS addressing: 16B units, unit' = unit ^ (row&15)  ----
// short-index of unit `u` (0..15) in row `r` of a [rows][128]-short tile
__device__ __forceinline__ int swz8(int r, int u) {
    return (r << 7) + (((u ^ r) & 15) << 3);
}
// short-index of scalar element (r, col)
__device__ __forceinline__ int swze(int r, int col) {
    return (r << 7) + ((((col >> 3) ^ r) & 15) << 3) + (col & 7);
}

// ---- staging helpers (caller syncs) ----

// Ws rows 0..127 <- W16[g][woff..]; 2 threads/row, 8 units each
__device__ __forceinline__ void stage_W16(const unsigned short* __restrict__ W16,
                                          int ldw, int woff,
                                          unsigned short* Ws, int tid)
{
    const int g  = tid >> 1;
    const int ub = (tid & 1) << 3;     // unit base 0 or 8
    const unsigned short* src = W16 + (size_t)g * ldw + woff + (ub << 3);
    #pragma unroll
    for (int j = 0; j < 8; ++j)
        *(s16x8*)&Ws[swz8(g, ub + j)] = *(const s16x8*)(src + j * 8);
}

// As rows 0..63 <- bf16(A32[row0+r]); 4 threads/row, 4 units each
__device__ __forceinline__ void stage_A32(const float* __restrict__ A, int row0,
                                          unsigned short* As, int tid)
{
    const int r  = tid & 63;
    const int ub = (tid >> 6) << 2;    // unit base 0,4,8,12
    int gr = row0 + r; if (gr >= NM) gr = NM - 1;
    const float* ap = A + (size_t)gr * HD + (ub << 3);
    #pragma unroll
    for (int j = 0; j < 4; ++j) {
        s16x8 s;
        #pragma unroll
        for (int q = 0; q < 8; ++q) s[q] = (short)f2b(ap[j * 8 + q]);
        *(s16x8*)&As[swz8(r, ub + j)] = s;
    }
}

__device__ __forceinline__ void stage_A16(const unsigned short* __restrict__ A16, int row0,
                                          unsigned short* As, int tid)
{
    const int r  = tid & 63;
    const int ub = (tid >> 6) << 2;
    int gr = row0 + r; if (gr >= NM) gr = NM - 1;
    const unsigned short* ap = A16 + (size_t)gr * HD + (ub << 3);
    #pragma unroll
    for (int j = 0; j < 4; ++j)
        *(s16x8*)&As[swz8(r, ub + j)] = *(const s16x8*)(ap + j * 8);
}

// global bf16 rows [row0..row0+63] <- LDS rows 0..63
__device__ __forceinline__ void lds_to_g16(const unsigned short* L, int row0,
                                           unsigned short* __restrict__ G, int tid)
{
    const int r  = tid & 63;
    const int ub = (tid >> 6) << 2;
    const int gr = row0 + r;
    if (gr >= NM) return;
    #pragma unroll
    for (int j = 0; j < 4; ++j)
        *(s16x8*)&G[(size_t)gr * HD + ((ub + j) << 3)] = *(const s16x8*)&L[swz8(r, ub + j)];
}

// acc[nf] += As(64 rows) @ Ws(rows nf*16..)^T over K=128, swizzled reads
__device__ __forceinline__ void mfma_128(const unsigned short* As,
                                         const unsigned short* Ws,
                                         int w, int l, fx4 (&acc)[8])
{
    const int rb = w * 16 + (l & 15);
    const int cu = l >> 4;             // unit sub-index 0..3
    #pragma unroll
    for (int ks = 0; ks < 4; ++ks) {
        const s16x8 a = *(const s16x8*)&As[swz8(rb, ks * 4 + cu)];
        #pragma unroll
        for (int nf = 0; nf < 8; ++nf) {
            const int rw = nf * 16 + (l & 15);
            const s16x8 b = *(const s16x8*)&Ws[swz8(rw, ks * 4 + cu)];
            acc[nf] = MFMA16(a, b, acc[nf]);
        }
    }
}

#define ZACC(acc) { _Pragma("unroll") for (int z_ = 0; z_ < 8; ++z_) \
                    acc[z_] = (fx4)0.0f; }

// ---------- weight fp32 -> bf16 conversion ----------
__global__ __launch_bounds__(256)
void dgru_wcvt(const float* __restrict__ Wz, const float* __restrict__ Wr,
               const float* __restrict__ Ur, const float* __restrict__ Wh,
               unsigned short* __restrict__ w16)
{
    const int i = blockIdx.x * 256 + threadIdx.x;
    float v;
    if      (i < 32768) v = Wz[i];
    else if (i < 49152) v = Wr[i - 32768];
    else if (i < 65536) v = Ur[i - 49152];
    else                v = Wh[i - 65536];
    w16[i] = f2b(v);
}

// ---------- pre: fmess16 + pre_r16 + h0 + Uh0 ----------
__global__ __launch_bounds__(256)
void dgru_pre(const float* __restrict__ fmess,
              const unsigned short* __restrict__ wz16,
              const unsigned short* __restrict__ wr16,
              const unsigned short* __restrict__ wh16,
              const unsigned short* __restrict__ ur16,
              const float* __restrict__ bz, const float* __restrict__ bh,
              const float* __restrict__ bur,
              unsigned short* __restrict__ fmess16,
              unsigned short* __restrict__ pre_r16,
              unsigned short* __restrict__ h16, unsigned short* __restrict__ uh16)
{
    __shared__ unsigned short As[BM * HD];     // 16 KB
    __shared__ unsigned short Ws[HD * HD];     // 32 KB
    const int tid  = threadIdx.x;
    const int row0 = blockIdx.x * BM;
    const int w    = tid >> 6;
    const int l    = tid & 63;

    stage_A32(fmess, row0, As, tid);
    stage_W16(wz16, 2 * HD, 0, Ws, tid);   // Wz1
    __syncthreads();

    lds_to_g16(As, row0, fmess16, tid);    // persist bf16 fmess for zh recompute

    fx4 accz[8]; ZACC(accz);
    mfma_128(As, Ws, w, l, accz);
    __syncthreads();                       // Ws readers done

    stage_W16(wr16, HD, 0, Ws, tid);
    __syncthreads();
    {
        fx4 accr[8]; ZACC(accr);
        mfma_128(As, Ws, w, l, accr);
        __syncthreads();                   // Ws readers done
        #pragma unroll
        for (int nf = 0; nf < 8; ++nf) {
            const int col = nf * 16 + (l & 15);
            #pragma unroll
            for (int q = 0; q < 4; ++q) {
                const int rl = w * 16 + ((l >> 4) << 2) + q;
                Ws[swze(rl, col)] = f2b(accr[nf][q]);
            }
        }
        __syncthreads();
        lds_to_g16(Ws, row0, pre_r16, tid);
        __syncthreads();                   // pre_r copies done before Wh restage
    }

    stage_W16(wh16, 2 * HD, 0, Ws, tid);   // Wh1
    __syncthreads();
    {
        fx4 acch[8]; ZACC(acch);
        mfma_128(As, Ws, w, l, acch);
        __syncthreads();                   // As & Ws readers done
        #pragma unroll
        for (int nf = 0; nf < 8; ++nf) {
            const int col = nf * 16 + (l & 15);
            const float bvz = bz[col];
            const float bvh = bh[col];
            #pragma unroll
            for (int q = 0; q < 4; ++q) {
                const int rl = w * 16 + ((l >> 4) << 2) + q;
                const int gr = row0 + rl;
                float h0 = sigm_f(accz[nf][q] + bvz) * tanh_f(acch[nf][q] + bvh);
                if (gr == 0) h0 = 0.0f;
                As[swze(rl, col)] = f2b(h0);
            }
        }
    }
    stage_W16(ur16, HD, 0, Ws, tid);
    __syncthreads();                       // h0 writes visible; Ws staged

    lds_to_g16(As, row0, h16, tid);
    {
        fx4 accu[8]; ZACC(accu);
        mfma_128(As, Ws, w, l, accu);
        __syncthreads();                   // Ws readers done
        #pragma unroll
        for (int nf = 0; nf < 8; ++nf) {
            const int col = nf * 16 + (l & 15);
            const float bv = bur[col];
            #pragma unroll
            for (int q = 0; q < 4; ++q) {
                const int rl = w * 16 + ((l >> 4) << 2) + q;
                Ws[swze(rl, col)] = f2b(accu[nf][q] + bv);
            }
        }
        __syncthreads();
        lds_to_g16(Ws, row0, uh16, tid);
    }
}

// ---------- gather (standalone, high occupancy): bf16 in, bf16 sums out ----------
__global__ __launch_bounds__(256)
void dgru_gather(const unsigned short* __restrict__ h16,
                 const unsigned short* __restrict__ uh16,
                 const int* __restrict__ bgraph,
                 const unsigned short* __restrict__ pre_r16,
                 unsigned short* __restrict__ sh16, unsigned short* __restrict__ sg16)
{
    const int tid = threadIdx.x;
    const int n   = blockIdx.x * 8 + (tid >> 5);   // grid covers NM exactly
    const int d0  = (tid & 31) << 2;

    const int4* bg = (const int4*)(bgraph + (size_t)n * KNEI);
    const int4 b0 = bg[0], b1 = bg[1];
    const int idx[KNEI] = {b0.x, b0.y, b0.z, b0.w, b1.x, b1.y, b1.z, b1.w};

    s16x4 hr[KNEI], ur[KNEI];
    #pragma unroll
    for (int k = 0; k < KNEI; ++k)
        hr[k] = *(const s16x4*)&h16[(size_t)idx[k] * HD + d0];
    #pragma unroll
    for (int k = 0; k < KNEI; ++k)
        ur[k] = *(const s16x4*)&uh16[(size_t)idx[k] * HD + d0];
    const s16x4 prb = *(const s16x4*)&pre_r16[(size_t)n * HD + d0];
    float pr[4];
    #pragma unroll
    for (int j = 0; j < 4; ++j) pr[j] = b2f((unsigned short)prb[j]);

    float sh[4] = {0.f, 0.f, 0.f, 0.f};
    float sg[4] = {0.f, 0.f, 0.f, 0.f};
    #pragma unroll
    for (int k = 0; k < KNEI; ++k) {
        #pragma unroll
        for (int j = 0; j < 4; ++j) {
            const float hv = b2f((unsigned short)hr[k][j]);
            const float uv = b2f((unsigned short)ur[k][j]);
            sh[j] += hv;
            sg[j] = fmaf(sigm_f(pr[j] + uv), hv, sg[j]);
        }
    }
    s16x4 osh, osg;
    #pragma unroll
    for (int j = 0; j < 4; ++j) {
        osh[j] = (short)f2b(sh[j]);
        osg[j] = (short)f2b(sg[j]);
    }
    const size_t o = (size_t)n * HD + d0;
    *(s16x4*)&sh16[o] = osh;
    *(s16x4*)&sg16[o] = osg;
}

// ---------- zh: recompute pre-acts from fmess16; z + GRU-update + next Uh ----------
__global__ __launch_bounds__(256)
void dgru_zh(const unsigned short* __restrict__ fmess16,
             const unsigned short* __restrict__ sh16,
             const unsigned short* __restrict__ sg16,
             const unsigned short* __restrict__ wz16,
             const unsigned short* __restrict__ wh16,
             const unsigned short* __restrict__ ur16,
             const float* __restrict__ bz, const float* __restrict__ bh,
             const float* __restrict__ bur,
             unsigned short* __restrict__ h16, unsigned short* __restrict__ uh16,
             float* __restrict__ hout, int last)
{
    __shared__ unsigned short AsF[BM * HD];    // fmess16 tile, later new h
    __shared__ unsigned short AsX[BM * HD];    // sum_h, then sum_g, then new Uh
    __shared__ unsigned short Ws[HD * HD];
    const int tid  = threadIdx.x;
    const int row0 = blockIdx.x * BM;
    const int w    = tid >> 6;
    const int l    = tid & 63;

    // ---- z = sigmoid(fmess@Wz1 + sum_h@Wz2 + bz) ----
    stage_A16(fmess16, row0, AsF, tid);
    stage_A16(sh16, row0, AsX, tid);
    stage_W16(wz16, 2 * HD, 0, Ws, tid);       // Wz1
    __syncthreads();                           // S1
    fx4 acc[8]; ZACC(acc);
    mfma_128(AsF, Ws, w, l, acc);
    __syncthreads();                           // S2: Ws readers done
    stage_W16(wz16, 2 * HD, HD, Ws, tid);      // Wz2
    __syncthreads();                           // S3
    mfma_128(AsX, Ws, w, l, acc);

    fx4 zres[8];
    float shv[8][4];
    #pragma unroll
    for (int nf = 0; nf < 8; ++nf) {
        const int col = nf * 16 + (l & 15);
        const float bv = bz[col];
        #pragma unroll
        for (int q = 0; q < 4; ++q) {
            const int rl = w * 16 + ((l >> 4) << 2) + q;
            zres[nf][q] = sigm_f(acc[nf][q] + bv);
            shv[nf][q]  = b2f(AsX[swze(rl, col)]);   // save sum_h before AsX reuse
        }
    }
    __syncthreads();                           // S4: AsX & Ws readers done

    // ---- pre_h = fmess@Wh1 + sum_g@Wh2 + bh ; h = (1-z)*sum_h + z*tanh(pre_h) ----
    stage_A16(sg16, row0, AsX, tid);
    stage_W16(wh16, 2 * HD, 0, Ws, tid);       // Wh1
    __syncthreads();                           // S5
    ZACC(acc);
    mfma_128(AsF, Ws, w, l, acc);
    __syncthreads();                           // S6: AsF & Ws readers done
    stage_W16(wh16, 2 * HD, HD, Ws, tid);      // Wh2
    __syncthreads();                           // S7
    mfma_128(AsX, Ws, w, l, acc);

    #pragma unroll
    for (int nf = 0; nf < 8; ++nf) {
        const int col = nf * 16 + (l & 15);
        const float bv = bh[col];
        #pragma unroll
        for (int q = 0; q < 4; ++q) {
            const int rl = w * 16 + ((l >> 4) << 2) + q;
            const int gr = row0 + rl;
            const float zz = zres[nf][q];
            float o = (1.0f - zz) * shv[nf][q] + zz * tanh_f(acc[nf][q] + bv);
            if (gr == 0) o = 0.0f;
            if (last) {
                if (gr < NM) hout[(size_t)gr * HD + col] = o;
            } else {
                AsF[swze(rl, col)] = f2b(o);   // AsF readers finished at S6
            }
        }
    }
    if (last) return;
    __syncthreads();                           // S8: h writes visible; AsX/Ws readers done

    // ---- Uh = h @ Ur.T + bur ----
    stage_W16(ur16, HD, 0, Ws, tid);
    lds_to_g16(AsF, row0, h16, tid);
    __syncthreads();                           // S9
    ZACC(acc);
    mfma_128(AsF, Ws, w, l, acc);
    #pragma unroll
    for (int nf = 0; nf < 8; ++nf) {
        const int col = nf * 16 + (l & 15);
        const float bv = bur[col];
        #pragma unroll
        for (int q = 0; q < 4; ++q) {
            const int rl = w * 16 + ((l >> 4) << 2) + q;
            AsX[swze(rl, col)] = f2b(acc[nf][q] + bv);   // AsX readers done at S8
        }
    }
    __syncthreads();                           // S10
    lds_to_g16(AsX, row0, uh16, tid);
}

extern "C" void kernel_launch(void* const* d_in, const int* in_sizes, int n_in,
                              void* d_out, int out_size, void* d_ws, size_t ws_size,
                              hipStream_t stream) {
    const float* fmess  = (const float*)d_in[0];
    const int*   bgraph = (const int*)  d_in[1];
    const float* W_z    = (const float*)d_in[2];
    const float* b_z    = (const float*)d_in[3];
    const float* W_r    = (const float*)d_in[4];
    const float* U_r    = (const float*)d_in[5];
    const float* b_Ur   = (const float*)d_in[6];
    const float* W_h    = (const float*)d_in[7];
    const float* b_h    = (const float*)d_in[8];

    unsigned short* ws16 = (unsigned short*)d_ws;
    unsigned short* fmess16 = ws16;
    unsigned short* pre_r16 = ws16 + NH;
    unsigned short* h16     = ws16 + 2 * NH;
    unsigned short* uh16    = ws16 + 3 * NH;
    unsigned short* sh16    = ws16 + 4 * NH;
    unsigned short* sg16    = ws16 + 5 * NH;
    unsigned short* w16     = ws16 + 6 * NH;
    unsigned short* wz16 = w16;                // [128][256]
    unsigned short* wr16 = w16 + 32768;        // [128][128]
    unsigned short* ur16 = w16 + 49152;        // [128][128]
    unsigned short* wh16 = w16 + 65536;        // [128][256]
    float* hout = (float*)d_out;
    // ws usage ~= 77 MB

    dgru_wcvt<<<dim3(384), dim3(256), 0, stream>>>(W_z, W_r, U_r, W_h, w16);

    dgru_pre<<<dim3(NBLK), dim3(256), 0, stream>>>(
        fmess, wz16, wr16, wh16, ur16, b_z, b_h, b_Ur,
        fmess16, pre_r16, h16, uh16);

    for (int it = 1; it < 5; ++it) {
        dgru_gather<<<dim3(NM / 8), dim3(256), 0, stream>>>(
            h16, uh16, bgraph, pre_r16, sh16, sg16);
        dgru_zh<<<dim3(NBLK), dim3(256), 0, stream>>>(
            fmess16, sh16, sg16, wz16, wh16, ur16, b_z, b_h, b_Ur,
            h16, uh16, hout, (it == 4) ? 1 : 0);
    }
}

// Round 13
// 336.443 us; speedup vs baseline: 1.1171x; 1.1171x over previous
//
#include <hip/hip_runtime.h>
#include <hip/hip_bf16.h>

#define NM 50000
#define HD 128
#define KNEI 8
#define BM 64
#define SPAD 136
#define NBLK ((NM + BM - 1) / BM)   // 782
#define NH ((size_t)NM * (size_t)HD)

typedef float  fx4   __attribute__((ext_vector_type(4)));
typedef short  s16x8 __attribute__((ext_vector_type(8)));
typedef short  s16x4 __attribute__((ext_vector_type(4)));

__device__ __forceinline__ float sigm_f(float x) {
    return __builtin_amdgcn_rcpf(1.0f + __expf(-x));
}
__device__ __forceinline__ float tanh_f(float x) {
    return 2.0f * sigm_f(2.0f * x) - 1.0f;
}
__device__ __forceinline__ unsigned short f2b(float f) {
    __hip_bfloat16 h = __float2bfloat16(f);
    return __builtin_bit_cast(unsigned short, h);
}
__device__ __forceinline__ float b2f(unsigned short u) {
    __hip_bfloat16 h = __builtin_bit_cast(__hip_bfloat16, u);
    return __bfloat162float(h);
}

#define MFMA16(a, b, c) __builtin_amdgcn_mfma_f32_16x16x32_bf16(a, b, c, 0, 0, 0)

// ---- register B-fragments straight from global (L2-hot weights, no LDS) ----
// bf[j][ks]: cols (nf0+j)*16..+16, k-slice ks*32..+32
__device__ __forceinline__ void load_bfrag(const unsigned short* __restrict__ W,
                                           int ldw, int woff, int nf0, int l,
                                           s16x8 (&bf)[2][4])
{
    #pragma unroll
    for (int j = 0; j < 2; ++j) {
        const unsigned short* p =
            W + (size_t)((nf0 + j) * 16 + (l & 15)) * ldw + woff + ((l >> 4) << 3);
        #pragma unroll
        for (int ks = 0; ks < 4; ++ks)
            bf[j][ks] = *(const s16x8*)(p + ks * 32);
    }
}

// acc[rb][j] += A(rows rb*16..) @ bf[j]^T over K=128 (ks 0..3 in order)
__device__ __forceinline__ void pass(const unsigned short (*As)[SPAD],
                                     const s16x8 (&bf)[2][4],
                                     int l, fx4 (&acc)[4][2])
{
    const int kq = (l >> 4) << 3;
    #pragma unroll
    for (int ks = 0; ks < 4; ++ks)
        #pragma unroll
        for (int rb = 0; rb < 4; ++rb) {
            const s16x8 a = *(const s16x8*)&As[rb * 16 + (l & 15)][ks * 32 + kq];
            acc[rb][0] = MFMA16(a, bf[0][ks], acc[rb][0]);
            acc[rb][1] = MFMA16(a, bf[1][ks], acc[rb][1]);
        }
}

#define ZACC2(acc) { _Pragma("unroll") for (int z_ = 0; z_ < 4; ++z_) { \
                     acc[z_][0] = (fx4)0.0f; acc[z_][1] = (fx4)0.0f; } }

// ---- A-tile staging / writeback (256 threads, caller syncs) ----
__device__ __forceinline__ void stage_A32(const float* __restrict__ A, int row0,
                                          unsigned short (*As)[SPAD], int tid)
{
    const int r  = tid & 63;
    const int c0 = (tid >> 6) << 5;
    int gr = row0 + r; if (gr >= NM) gr = NM - 1;
    const float* ap = A + (size_t)gr * HD + c0;
    #pragma unroll
    for (int j = 0; j < 32; j += 8) {
        s16x8 s;
        #pragma unroll
        for (int q = 0; q < 8; ++q) s[q] = (short)f2b(ap[j + q]);
        *(s16x8*)&As[r][c0 + j] = s;
    }
}

__device__ __forceinline__ void stage_A16(const unsigned short* __restrict__ A16, int row0,
                                          unsigned short (*As)[SPAD], int tid)
{
    const int r  = tid & 63;
    const int c0 = (tid >> 6) << 5;
    int gr = row0 + r; if (gr >= NM) gr = NM - 1;
    const unsigned short* ap = A16 + (size_t)gr * HD + c0;
    #pragma unroll
    for (int j = 0; j < 32; j += 8)
        *(s16x8*)&As[r][c0 + j] = *(const s16x8*)(ap + j);
}

__device__ __forceinline__ void lds_to_g16(const unsigned short (*L)[SPAD], int row0,
                                           unsigned short* __restrict__ G, int tid)
{
    const int r  = tid & 63;
    const int c0 = (tid >> 6) << 5;
    const int gr = row0 + r;
    if (gr >= NM) return;
    #pragma unroll
    for (int j = 0; j < 32; j += 8)
        *(s16x8*)&G[(size_t)gr * HD + c0 + j] = *(const s16x8*)&L[r][c0 + j];
}

// ---------- weight fp32 -> bf16 conversion ----------
__global__ __launch_bounds__(256)
void dgru_wcvt(const float* __restrict__ Wz, const float* __restrict__ Wr,
               const float* __restrict__ Ur, const float* __restrict__ Wh,
               unsigned short* __restrict__ w16)
{
    const int i = blockIdx.x * 256 + threadIdx.x;
    float v;
    if      (i < 32768) v = Wz[i];
    else if (i < 49152) v = Wr[i - 32768];
    else if (i < 65536) v = Ur[i - 49152];
    else                v = Wh[i - 65536];
    w16[i] = f2b(v);
}

// ---------- pre: fmess16 + pre_r16 + h0 + Uh0 (reg-weights, 5 barriers) ----------
__global__ __launch_bounds__(256, 3)
void dgru_pre(const float* __restrict__ fmess,
              const unsigned short* __restrict__ wz16,
              const unsigned short* __restrict__ wr16,
              const unsigned short* __restrict__ wh16,
              const unsigned short* __restrict__ ur16,
              const float* __restrict__ bz, const float* __restrict__ bh,
              const float* __restrict__ bur,
              unsigned short* __restrict__ fmess16,
              unsigned short* __restrict__ pre_r16,
              unsigned short* __restrict__ h16, unsigned short* __restrict__ uh16)
{
    __shared__ unsigned short AsF[BM][SPAD];
    __shared__ unsigned short AsX[BM][SPAD];
    const int tid  = threadIdx.x;
    const int row0 = blockIdx.x * BM;
    const int l    = tid & 63;
    const int nf0  = (tid >> 6) << 1;
    const int col0 = nf0 * 16 + (l & 15);
    const int rq   = (l >> 4) << 2;

    s16x8 bfA[2][4], bfB[2][4];
    load_bfrag(wz16, 2 * HD, 0, nf0, l, bfA);   // Wz1
    load_bfrag(wr16, HD, 0, nf0, l, bfB);       // Wr
    stage_A32(fmess, row0, AsF, tid);
    __syncthreads();                            // S1

    lds_to_g16(AsF, row0, fmess16, tid);        // persist bf16 fmess

    fx4 zacc[4][2]; ZACC2(zacc);
    pass(AsF, bfA, l, zacc);                    // fmess @ Wz1
    load_bfrag(wh16, 2 * HD, 0, nf0, l, bfA);   // Wh1 (bfA free)
    {
        fx4 racc[4][2]; ZACC2(racc);
        pass(AsF, bfB, l, racc);                // fmess @ Wr (no bias)
        #pragma unroll
        for (int rb = 0; rb < 4; ++rb)
            #pragma unroll
            for (int j = 0; j < 2; ++j)
                #pragma unroll
                for (int q = 0; q < 4; ++q)
                    AsX[rb * 16 + rq + q][col0 + j * 16] = f2b(racc[rb][j][q]);
    }
    __syncthreads();                            // S2
    lds_to_g16(AsX, row0, pre_r16, tid);

    fx4 hacc[4][2]; ZACC2(hacc);
    pass(AsF, bfA, l, hacc);                    // fmess @ Wh1
    load_bfrag(ur16, HD, 0, nf0, l, bfB);       // Ur
    #pragma unroll
    for (int rb = 0; rb < 4; ++rb)
        #pragma unroll
        for (int j = 0; j < 2; ++j) {
            const float bvz = bz[col0 + j * 16];
            const float bvh = bh[col0 + j * 16];
            #pragma unroll
            for (int q = 0; q < 4; ++q) {
                const int gr = row0 + rb * 16 + rq + q;
                float h0 = sigm_f(zacc[rb][j][q] + bvz) * tanh_f(hacc[rb][j][q] + bvh);
                if (gr == 0) h0 = 0.0f;
                hacc[rb][j][q] = h0;
            }
        }
    __syncthreads();                            // S3: pre_r copy readers done
    #pragma unroll
    for (int rb = 0; rb < 4; ++rb)
        #pragma unroll
        for (int j = 0; j < 2; ++j)
            #pragma unroll
            for (int q = 0; q < 4; ++q)
                AsX[rb * 16 + rq + q][col0 + j * 16] = f2b(hacc[rb][j][q]);
    __syncthreads();                            // S4
    lds_to_g16(AsX, row0, h16, tid);
    {
        fx4 uacc[4][2]; ZACC2(uacc);
        pass(AsX, bfB, l, uacc);                // h0 @ Ur
        #pragma unroll
        for (int rb = 0; rb < 4; ++rb)
            #pragma unroll
            for (int j = 0; j < 2; ++j) {
                const float bv = bur[col0 + j * 16];
                #pragma unroll
                for (int q = 0; q < 4; ++q)
                    AsF[rb * 16 + rq + q][col0 + j * 16] = f2b(uacc[rb][j][q] + bv);
            }
    }
    __syncthreads();                            // S5
    lds_to_g16(AsF, row0, uh16, tid);
}

// ---------- gather (standalone, high occupancy) ----------
__global__ __launch_bounds__(256)
void dgru_gather(const unsigned short* __restrict__ h16,
                 const unsigned short* __restrict__ uh16,
                 const int* __restrict__ bgraph,
                 const unsigned short* __restrict__ pre_r16,
                 unsigned short* __restrict__ sh16, unsigned short* __restrict__ sg16)
{
    const int tid = threadIdx.x;
    const int n   = blockIdx.x * 8 + (tid >> 5);
    const int d0  = (tid & 31) << 2;

    const int4* bg = (const int4*)(bgraph + (size_t)n * KNEI);
    const int4 b0 = bg[0], b1 = bg[1];
    const int idx[KNEI] = {b0.x, b0.y, b0.z, b0.w, b1.x, b1.y, b1.z, b1.w};

    s16x4 hr[KNEI], ur[KNEI];
    #pragma unroll
    for (int k = 0; k < KNEI; ++k)
        hr[k] = *(const s16x4*)&h16[(size_t)idx[k] * HD + d0];
    #pragma unroll
    for (int k = 0; k < KNEI; ++k)
        ur[k] = *(const s16x4*)&uh16[(size_t)idx[k] * HD + d0];
    const s16x4 prb = *(const s16x4*)&pre_r16[(size_t)n * HD + d0];
    float pr[4];
    #pragma unroll
    for (int j = 0; j < 4; ++j) pr[j] = b2f((unsigned short)prb[j]);

    float sh[4] = {0.f, 0.f, 0.f, 0.f};
    float sg[4] = {0.f, 0.f, 0.f, 0.f};
    #pragma unroll
    for (int k = 0; k < KNEI; ++k) {
        #pragma unroll
        for (int j = 0; j < 4; ++j) {
            const float hv = b2f((unsigned short)hr[k][j]);
            const float uv = b2f((unsigned short)ur[k][j]);
            sh[j] += hv;
            sg[j] = fmaf(sigm_f(pr[j] + uv), hv, sg[j]);
        }
    }
    s16x4 osh, osg;
    #pragma unroll
    for (int j = 0; j < 4; ++j) {
        osh[j] = (short)f2b(sh[j]);
        osg[j] = (short)f2b(sg[j]);
    }
    const size_t o = (size_t)n * HD + d0;
    *(s16x4*)&sh16[o] = osh;
    *(s16x4*)&sg16[o] = osg;
}

// ---------- zh: reg-weights, 6 barriers; z + GRU update + next Uh ----------
__global__ __launch_bounds__(256, 3)
void dgru_zh(const unsigned short* __restrict__ fmess16,
             const unsigned short* __restrict__ sh16,
             const unsigned short* __restrict__ sg16,
             const unsigned short* __restrict__ wz16,
             const unsigned short* __restrict__ wh16,
             const unsigned short* __restrict__ ur16,
             const float* __restrict__ bz, const float* __restrict__ bh,
             const float* __restrict__ bur,
             unsigned short* __restrict__ h16, unsigned short* __restrict__ uh16,
             float* __restrict__ hout, int last)
{
    __shared__ unsigned short AsF[BM][SPAD];   // fmess tile, later new h
    __shared__ unsigned short AsX[BM][SPAD];   // sum_h, then sum_g, then Uh
    const int tid  = threadIdx.x;
    const int row0 = blockIdx.x * BM;
    const int l    = tid & 63;
    const int nf0  = (tid >> 6) << 1;
    const int col0 = nf0 * 16 + (l & 15);
    const int rq   = (l >> 4) << 2;

    s16x8 bfA[2][4], bfB[2][4];
    load_bfrag(wz16, 2 * HD, 0,  nf0, l, bfA);  // Wz1
    load_bfrag(wz16, 2 * HD, HD, nf0, l, bfB);  // Wz2
    stage_A16(fmess16, row0, AsF, tid);
    stage_A16(sh16,    row0, AsX, tid);
    __syncthreads();                            // S1

    // z = sigmoid(fmess@Wz1 + sum_h@Wz2 + bz); sum_h captured packed
    fx4 zacc[4][2]; ZACC2(zacc);
    pass(AsF, bfA, l, zacc);
    pass(AsX, bfB, l, zacc);
    s16x4 shp[4][2];
    #pragma unroll
    for (int rb = 0; rb < 4; ++rb)
        #pragma unroll
        for (int j = 0; j < 2; ++j) {
            const float bv = bz[col0 + j * 16];
            #pragma unroll
            for (int q = 0; q < 4; ++q) {
                shp[rb][j][q] = (short)AsX[rb * 16 + rq + q][col0 + j * 16];
                zacc[rb][j][q] = sigm_f(zacc[rb][j][q] + bv);   // zacc now holds z
            }
        }
    load_bfrag(wh16, 2 * HD, 0,  nf0, l, bfA);  // Wh1
    load_bfrag(wh16, 2 * HD, HD, nf0, l, bfB);  // Wh2
    __syncthreads();                            // S2: AsX readers done
    stage_A16(sg16, row0, AsX, tid);
    __syncthreads();                            // S3

    // h = (1-z)*sum_h + z*tanh(fmess@Wh1 + sum_g@Wh2 + bh)
    fx4 hacc[4][2]; ZACC2(hacc);
    pass(AsF, bfA, l, hacc);
    pass(AsX, bfB, l, hacc);
    #pragma unroll
    for (int rb = 0; rb < 4; ++rb)
        #pragma unroll
        for (int j = 0; j < 2; ++j) {
            const float bv = bh[col0 + j * 16];
            #pragma unroll
            for (int q = 0; q < 4; ++q) {
                const int gr = row0 + rb * 16 + rq + q;
                const float zz = zacc[rb][j][q];
                const float sv = b2f((unsigned short)shp[rb][j][q]);
                float o = (1.0f - zz) * sv + zz * tanh_f(hacc[rb][j][q] + bv);
                if (gr == 0) o = 0.0f;
                hacc[rb][j][q] = o;
            }
        }
    if (last) {
        #pragma unroll
        for (int rb = 0; rb < 4; ++rb)
            #pragma unroll
            for (int j = 0; j < 2; ++j)
                #pragma unroll
                for (int q = 0; q < 4; ++q) {
                    const int gr = row0 + rb * 16 + rq + q;
                    if (gr < NM) hout[(size_t)gr * HD + col0 + j * 16] = hacc[rb][j][q];
                }
        return;
    }
    load_bfrag(ur16, HD, 0, nf0, l, bfA);       // Ur
    __syncthreads();                            // S4: AsF readers done
    #pragma unroll
    for (int rb = 0; rb < 4; ++rb)
        #pragma unroll
        for (int j = 0; j < 2; ++j)
            #pragma unroll
            for (int q = 0; q < 4; ++q)
                AsF[rb * 16 + rq + q][col0 + j * 16] = f2b(hacc[rb][j][q]);
    __syncthreads();                            // S5
    lds_to_g16(AsF, row0, h16, tid);
    {
        fx4 uacc[4][2]; ZACC2(uacc);
        pass(AsF, bfA, l, uacc);                // h @ Ur
        #pragma unroll
        for (int rb = 0; rb < 4; ++rb)
            #pragma unroll
            for (int j = 0; j < 2; ++j) {
                const float bv = bur[col0 + j * 16];
                #pragma unroll
                for (int q = 0; q < 4; ++q)
                    AsX[rb * 16 + rq + q][col0 + j * 16] = f2b(uacc[rb][j][q] + bv);
            }
    }
    __syncthreads();                            // S6
    lds_to_g16(AsX, row0, uh16, tid);
}

extern "C" void kernel_launch(void* const* d_in, const int* in_sizes, int n_in,
                              void* d_out, int out_size, void* d_ws, size_t ws_size,
                              hipStream_t stream) {
    const float* fmess  = (const float*)d_in[0];
    const int*   bgraph = (const int*)  d_in[1];
    const float* W_z    = (const float*)d_in[2];
    const float* b_z    = (const float*)d_in[3];
    const float* W_r    = (const float*)d_in[4];
    const float* U_r    = (const float*)d_in[5];
    const float* b_Ur   = (const float*)d_in[6];
    const float* W_h    = (const float*)d_in[7];
    const float* b_h    = (const float*)d_in[8];

    unsigned short* ws16 = (unsigned short*)d_ws;
    unsigned short* fmess16 = ws16;
    unsigned short* pre_r16 = ws16 + NH;
    unsigned short* h16     = ws16 + 2 * NH;
    unsigned short* uh16    = ws16 + 3 * NH;
    unsigned short* sh16    = ws16 + 4 * NH;
    unsigned short* sg16    = ws16 + 5 * NH;
    unsigned short* w16     = ws16 + 6 * NH;
    unsigned short* wz16 = w16;                // [128][256]
    unsigned short* wr16 = w16 + 32768;        // [128][128]
    unsigned short* ur16 = w16 + 49152;        // [128][128]
    unsigned short* wh16 = w16 + 65536;        // [128][256]
    float* hout = (float*)d_out;
    // ws usage ~= 77 MB

    dgru_wcvt<<<dim3(384), dim3(256), 0, stream>>>(W_z, W_r, U_r, W_h, w16);

    dgru_pre<<<dim3(NBLK), dim3(256), 0, stream>>>(
        fmess, wz16, wr16, wh16, ur16, b_z, b_h, b_Ur,
        fmess16, pre_r16, h16, uh16);

    for (int it = 1; it < 5; ++it) {
        dgru_gather<<<dim3(NM / 8), dim3(256), 0, stream>>>(
            h16, uh16, bgraph, pre_r16, sh16, sg16);
        dgru_zh<<<dim3(NBLK), dim3(256), 0, stream>>>(
            fmess16, sh16, sg16, wz16, wh16, ur16, b_z, b_h, b_Ur,
            h16, uh16, hout, (it == 4) ? 1 : 0);
    }
}